// Round 16
// baseline (134.876 us; speedup 1.0000x reference)
//
#include <hip/hip_runtime.h>
#include <hip/hip_bf16.h>
#include <cmath>
#include <cstring>

#define B_TOT 16384

typedef unsigned int uint_t;
typedef unsigned short ushort_t;
typedef __attribute__((ext_vector_type(8))) short bf16x8;
typedef __attribute__((ext_vector_type(16))) float f32x16;

// workspace layout (bytes); total 6033408 (~5.76 MiB)
#define WS_TAB 0          // uint32[192]
#define WS_CSQ 1024       // double[64]
#define WS_LIN 4096       // float[16384][64] = 4 MiB (UNUSED after R9 fusion)
#define WS_S   4198400    // float[64][4096] = 1 MiB (prep_s -> prep_pack)
#define WS_PPK 5246976    // A-packs: 192 steps * 4 KiB = 786432
// pack frag addr: ((s*4 + mt*2 + plane)*64 + lane)*16 ; plane 0=hi 1=lo
// lane (r=lane&31,h=lane>>5) holds P[n=mt*32+r][kappa = s*16 + h*8 + e]

// ---------- prep 1: S[n][cell] = sum_k cq[n,k]*gamma[k][cell] (LDS-staged) ----
__global__ __launch_bounds__(256) void prep_s(const float* __restrict__ g,
                                              const float* __restrict__ cq,
                                              char* __restrict__ ws) {
  __shared__ float gl[128][68];
  __shared__ float cql[16][132];
  float* S = (float*)(ws + WS_S);
  const int ns = blockIdx.x >> 6, J = blockIdx.x & 63, t = threadIdx.x;
  for (int i = t; i < 2048; i += 256) {
    const int k = i >> 4, c4 = (i & 15) * 4;
    *(float4*)&gl[k][c4] = *(const float4*)(g + (size_t)k * 4096 + J * 64 + c4);
  }
  for (int i = t; i < 2048; i += 256) {
    const int n16 = i >> 7, k = i & 127;
    cql[n16][k] = cq[(ns * 16 + n16) * 128 + k];
  }
  __syncthreads();
  const int n16 = t >> 4, c4 = (t & 15) * 4;
  float4 acc = {0.f, 0.f, 0.f, 0.f};
#pragma unroll 8
  for (int k = 0; k < 128; ++k) {
    const float w = cql[n16][k];
    const float4 gv = *(const float4*)&gl[k][c4];
    acc.x = fmaf(w, gv.x, acc.x);
    acc.y = fmaf(w, gv.y, acc.y);
    acc.z = fmaf(w, gv.z, acc.z);
    acc.w = fmaf(w, gv.w, acc.w);
  }
  *(float4*)(S + (size_t)(ns * 16 + n16) * 4096 + J * 64 + c4) = acc;
}

// ---------- prep 2: build bf16 hi/lo A-packs + tab + csq (256 blocks) --------
__global__ __launch_bounds__(256) void prep_pack(
    const float* __restrict__ qfw, const float* __restrict__ cq,
    const float* __restrict__ qzw, const float* __restrict__ qzb,
    const float* __restrict__ qfb, char* __restrict__ ws) {
  __shared__ float Sl[4096];
  __shared__ uint_t tabl[192];
  __shared__ float psumf[128][2];
  const int n = blockIdx.x & 63, part = blockIdx.x >> 6, t = threadIdx.x;
  const float* __restrict__ S = (const float*)(ws + WS_S) + (size_t)n * 4096;
  for (int i = t; i < 4096; i += 256) Sl[i] = S[i];
  if (t < 64) {
    const int i = t;
    const int start = (i < 16) ? 4 * i
                     : (i < 32) ? 64 + 3 * (i - 16)
                     : (i < 48) ? 112 + 2 * (i - 32)
                                : 144 + (i - 48);
    const int nst = 4 - (i >> 4);
    for (int u = 0; u < nst; ++u)
      tabl[start + u] = (0u << 16) | ((uint_t)i << 8) | (uint_t)(16 * ((i >> 4) + u));
  } else if (t < 80) tabl[160 + (t - 64)] = (1u << 16) | (uint_t)((t - 64) * 16);
  else if (t < 84)   tabl[176 + (t - 80)] = (2u << 16) | (uint_t)((t - 80) * 16);
  else if (t == 84)  tabl[180] = (3u << 16);
  else if (t < 96)   tabl[181 + (t - 85)] = 0;
  __syncthreads();
  if (part == 0 && n == 0 && t < 192) ((uint_t*)(ws + WS_TAB))[t] = tabl[t];

  const int mt = n >> 5, r = n & 31;
  auto wpack = [&](int s, int jo, float val) {
    const __hip_bfloat16 hb = __float2bfloat16(val);
    const float hf = __bfloat162float(hb);
    const __hip_bfloat16 lb = __float2bfloat16(val - hf);
    ushort_t hu, lu;
    memcpy(&hu, &hb, 2);
    memcpy(&lu, &lb, 2);
    const size_t base =
        (((size_t)s * 4 + mt * 2) * 64 + ((jo >> 3) & 1) * 32 + r) * 16 + (jo & 7) * 2;
    *(ushort_t*)(ws + WS_PPK + base) = hu;
    *(ushort_t*)(ws + WS_PPK + base + 1024) = lu;
  };

  for (int v = part * 640 + t; v < (part + 1) * 640; v += 256) {
    const int s = v >> 4, jo = v & 15;
    const uint_t inf = tabl[s];
    const int i = (inf >> 8) & 255, j0 = inf & 255;
    const int j = j0 + jo;
    const float val =
        (j < i) ? 0.f : ((j > i) ? Sl[i * 64 + j] + Sl[j * 64 + i] : Sl[i * 64 + i]);
    wpack(s, jo, val);
  }
  const float* __restrict__ cqn = cq + n * 128;

  if (part >= 2) {
    const int fl = t & 127, kh = t >> 7;
    const int f = (part - 2) * 128 + fl;
    float a = 0.f;
#pragma unroll 8
    for (int k = 0; k < 64; ++k)
      a = fmaf(qfw[(kh * 64 + k) * 256 + f], cqn[kh * 64 + k], a);
    psumf[fl][kh] = a;
    __syncthreads();
    if (t < 128) {
      const int ff = (part - 2) * 128 + t;
      wpack(160 + (ff >> 4), ff & 15, psumf[t][0] + psumf[t][1]);
    }
  } else if (part == 1) {
    if (t < 64) {
      float a = 0.f;
#pragma unroll 8
      for (int k = 0; k < 128; ++k) a = fmaf(cqn[k], qzw[k * 64 + t], a);
      wpack(176 + (t >> 4), t & 15, a);
    }
    for (int v2 = t; v2 < 176; v2 += 256) wpack(181 + (v2 >> 4), v2 & 15, 0.f);
  } else {
    if (t == 128) {
      float a = 0.f;
      for (int k = 0; k < 128; ++k) a = fmaf(qzb[k] + qfb[k], cqn[k], a);
      wpack(180, 0, a);
    } else if (t > 128 && t < 144) wpack(180, t - 128, 0.f);
    if (t == 144) {
      double a = 0.0;
      for (int d = 0; d < 64; ++d) a = fma((double)cqn[d], (double)cqn[d], a);
      ((double*)(ws + WS_CSQ))[n] = a;
    }
  }
}

// ---------- fused gemm+tail: 512 blocks x 256 thr (4 waves), 32 rows/block --
// R23: single change vs R22 — 2 -> 4 accumulators to break the MFMA
// dependency chain. R22 chained 3 dependent MFMAs per step per acc
// (Ah·Bh -> Ah·Bl -> Al·Bh), a 138-deep serial chain across 46 steps that
// the compiler CANNOT reassociate (FP). Now acc0: Ah0·Bh (chain 1/step);
// acc1: Ah0·Bl -> Al0·Bh (chain 2/step); acc2/acc3 mirror mt=1. Fold sums
// acc0+acc1 / acc2+acc3 (tiny reassociation, within tolerance per R17
// precedent). +32 VGPR -> ~112 < 128 cap of (256,4).
// Kept: R9 serialization cuts, R11 depth-2 ping-pong, R12/R17 f32 tail.
// Closed axes (measured): wave count (R4/R8/R12), tab decode (R7), LDS
// A-staging (R8/R15), prefetch depth 3 (R14).
__global__ __launch_bounds__(256, 4) void gemm_tail_kernel(
    const float* __restrict__ z, const float* __restrict__ feat,
    const float* __restrict__ cq, char* __restrict__ ws,
    float* __restrict__ out) {
  __shared__ __align__(16) unsigned char smem[46208];
  // --- gemm phase ---
  float (*z_lds)[68] = (float (*)[68])(smem);        // 8704 (dead after loop)
  float (*slin)[65] = (float (*)[65])(smem + 8704);  // region 0 (live thru tail)
  // fold regions w=0..3 at byte 8704 + w*8320 (float offset w*2080);
  // regions 1..3 (17024..41984) dead after the sum pass.
  // --- tail phase (overlays regions 1..3) ---
  float (*zt)[33] = (float (*)[33])(smem + 17024);       // 8448 -> 25472
  float (*cqT)[65] = (float (*)[65])(smem + 25472);      // 16640 -> 42112
  double (*s_exp)[65] = (double (*)[65])(smem + 25472);  // overlay cqT ([32] rows)
  double (*pmax)[9] = (double (*)[9])(smem + 42112);     // 2304 -> 44416
  int (*parg)[9] = (int (*)[9])(smem + 44416);           // 1152 -> 45568
  double* rowmax = (double*)(smem + 45568);              // 256 -> 45824
  int* rowarg = (int*)(smem + 45824);                    // 128 -> 45952
  double* rowinv = (double*)(smem + 45952);              // 256 -> 46208

  const int t = threadIdx.x, lane = t & 63;
  const int wv = __builtin_amdgcn_readfirstlane(t >> 6);  // 0..3
  const int b0 = blockIdx.x * 32;
  const int h = lane >> 5, c = lane & 31;

  // feat preload: wave wv's mode-1 steps are s = 160+4m+wv, m=0..3.
  float4 fva[4], fvb[4];
#pragma unroll
  for (int m = 0; m < 4; ++m) {
    const float* __restrict__ fp =
        feat + (size_t)(b0 + c) * 256 + (4 * m + wv) * 16 + h * 8;
    fva[m] = *(const float4*)fp;
    fvb[m] = *(const float4*)(fp + 4);
  }

  for (int i = t; i < 2048; i += 256) z_lds[i >> 6][i & 63] = z[(size_t)b0 * 64 + i];
  if (t < 128) z_lds[t >> 2][64 + (t & 3)] = 0.f;
  __syncthreads();

  const bf16x8* __restrict__ pp = (const bf16x8*)(ws + WS_PPK);
  f32x16 acc0 = {}, acc1 = {}, acc2 = {}, acc3 = {};

  // RNE hi/lo split + 6 MFMAs (4-acc split: max 2 dependent MFMAs per acc)
  auto do_step = [&](const float* xv, bf16x8 Ah0, bf16x8 Al0, bf16x8 Ah1,
                     bf16x8 Al1) {
    uint_t bhw[4], blw[4];
#pragma unroll
    for (int e2 = 0; e2 < 4; ++e2) {
      const float2 xp = {xv[2 * e2], xv[2 * e2 + 1]};
      const __hip_bfloat162 hb2 = __float22bfloat162_rn(xp);
      uint_t hw;
      memcpy(&hw, &hb2, 4);
      const float h0 = __uint_as_float(hw << 16);
      const float h1 = __uint_as_float(hw & 0xffff0000u);
      const float2 lp = {xp.x - h0, xp.y - h1};
      const __hip_bfloat162 lb2 = __float22bfloat162_rn(lp);
      uint_t lw;
      memcpy(&lw, &lb2, 4);
      bhw[e2] = hw;
      blw[e2] = lw;
    }
    bf16x8 Bh, Bl;
    memcpy(&Bh, bhw, 16);
    memcpy(&Bl, blw, 16);
    acc0 = __builtin_amdgcn_mfma_f32_32x32x16_bf16(Ah0, Bh, acc0, 0, 0, 0);
    acc1 = __builtin_amdgcn_mfma_f32_32x32x16_bf16(Ah0, Bl, acc1, 0, 0, 0);
    acc1 = __builtin_amdgcn_mfma_f32_32x32x16_bf16(Al0, Bh, acc1, 0, 0, 0);
    acc2 = __builtin_amdgcn_mfma_f32_32x32x16_bf16(Ah1, Bh, acc2, 0, 0, 0);
    acc3 = __builtin_amdgcn_mfma_f32_32x32x16_bf16(Ah1, Bl, acc3, 0, 0, 0);
    acc3 = __builtin_amdgcn_mfma_f32_32x32x16_bf16(Al1, Bh, acc3, 0, 0, 0);
  };

  // mode-0 B build for step s (branch-free decode, LDS reads)
  auto build_xv0 = [&](int s, float* xv) {
    int i_idx, p0;
    if (s < 64) {
      i_idx = s >> 2; p0 = (s & 3) * 16;
    } else if (s < 112) {
      const int q = s - 64, d = (q * 86) >> 8;  // d = q/3 exact for q<48
      i_idx = 16 + d; p0 = (q - 3 * d + 1) * 16;
    } else if (s < 144) {
      const int q = s - 112;
      i_idx = 32 + (q >> 1); p0 = ((q & 1) + 2) * 16;
    } else {
      i_idx = s - 96; p0 = 48;
    }
    const float zi = z_lds[c][i_idx];
    const float* __restrict__ zp = &z_lds[c][p0 + h * 8];
    const float4 a = *(const float4*)zp, b2 = *(const float4*)(zp + 4);
    xv[0] = zi * a.x; xv[1] = zi * a.y; xv[2] = zi * a.z; xv[3] = zi * a.w;
    xv[4] = zi * b2.x; xv[5] = zi * b2.y; xv[6] = zi * b2.z; xv[7] = zi * b2.w;
  };

  // R11 main loop: 40 mode-0 steps as 20 depth-2 ping-pong pairs.
  // pA_ holds step sA = wv+8*p; pB_ holds sB = sA+4.
  bf16x8 pA0, pA1, pA2, pA3, pB0, pB1, pB2, pB3;
  {
    const size_t b4 = (size_t)wv * 256;  // step wv * 4 frags * 64 lanes
    pA0 = pp[b4 + lane]; pA1 = pp[b4 + 64 + lane];
    pA2 = pp[b4 + 128 + lane]; pA3 = pp[b4 + 192 + lane];
  }
#pragma unroll 2
  for (int p = 0; p < 20; ++p) {
    const int sA = wv + p * 8, sB = sA + 4;
    {  // issue loads for sB (consumed after compute(sA))
      const size_t b4 = (size_t)sB * 256;
      pB0 = pp[b4 + lane]; pB1 = pp[b4 + 64 + lane];
      pB2 = pp[b4 + 128 + lane]; pB3 = pp[b4 + 192 + lane];
    }
    {
      float xv[8];
      build_xv0(sA, xv);
      do_step(xv, pA0, pA1, pA2, pA3);
    }
    if (p < 19) {  // issue loads for next pair's sA (consumed after compute(sB))
      const size_t b4 = (size_t)(sA + 8) * 256;
      pA0 = pp[b4 + lane]; pA1 = pp[b4 + 64 + lane];
      pA2 = pp[b4 + 128 + lane]; pA3 = pp[b4 + 192 + lane];
    }
    {
      float xv[8];
      build_xv0(sB, xv);
      do_step(xv, pB0, pB1, pB2, pB3);
    }
  }
  // epilogue its 40..45 (A loads direct; latency-light, 6 of 46 steps)
  auto do_mfma_g = [&](const float* xv, int s) {
    const bf16x8 Ah0 = pp[((size_t)s * 4 + 0) * 64 + lane];
    const bf16x8 Al0 = pp[((size_t)s * 4 + 1) * 64 + lane];
    const bf16x8 Ah1 = pp[((size_t)s * 4 + 2) * 64 + lane];
    const bf16x8 Al1 = pp[((size_t)s * 4 + 3) * 64 + lane];
    do_step(xv, Ah0, Al0, Ah1, Al1);
  };
#pragma unroll
  for (int m = 0; m < 4; ++m) {
    const float xv[8] = {fva[m].x, fva[m].y, fva[m].z, fva[m].w,
                         fvb[m].x, fvb[m].y, fvb[m].z, fvb[m].w};
    do_mfma_g(xv, 160 + 4 * m + wv);
  }
  {
    const float* __restrict__ zp = &z_lds[c][wv * 16 + h * 8];
    const float4 a = *(const float4*)zp, b2 = *(const float4*)(zp + 4);
    const float xv[8] = {a.x, a.y, a.z, a.w, b2.x, b2.y, b2.z, b2.w};
    do_mfma_g(xv, 176 + wv);
  }
  {
    const float xv[8] = {(h == 0) ? 1.f : 0.f, 0.f, 0.f, 0.f, 0.f, 0.f, 0.f, 0.f};
    do_mfma_g(xv, 180 + wv);
  }

  // fold: per-wave plain writes (conflict-free; full (c,n) coverage)
  // mt=0 -> acc0+acc1 ; mt=1 -> acc2+acc3
  {
    float* __restrict__ slw = (float*)(smem + 8704) + wv * 2080;
#pragma unroll
    for (int r = 0; r < 16; ++r) {
      const int n0 = (r & 3) + 8 * (r >> 2) + 4 * h;
      slw[c * 65 + n0] = acc0[r] + acc1[r];
      slw[c * 65 + 32 + n0] = acc2[r] + acc3[r];
    }
  }
  __syncthreads();
  // sum 4 wave regions into region 0
  for (int idx = t; idx < 2048; idx += 256) {
    const int c0 = idx >> 6, n0 = idx & 63;
    float* __restrict__ base = (float*)(smem + 8704) + c0 * 65 + n0;
    base[0] = (base[0] + base[2080]) + (base[4160] + base[6240]);
  }
  __syncthreads();

  // --- tail staging (overwrites dead regions 1..3) ---
  for (int i = t; i < 2048; i += 256) zt[i & 63][i >> 6] = z[(size_t)b0 * 64 + i];
  for (int i = t; i < 4096; i += 256) {
    const int n = i >> 6, ii = i & 63;
    cqT[ii][n] = cq[n * 128 + ii];
  }
  __syncthreads();

  // --- tail phase ---
  const int r = t & 31, cg = t >> 5;

  // R17: f32 direct-diff dist_sq (reference formulation; no cancellation)
  float z_sqf = 0.f;
  float dsq[8] = {0.f, 0.f, 0.f, 0.f, 0.f, 0.f, 0.f, 0.f};
#pragma unroll 4
  for (int i = 0; i < 64; ++i) {
    const float zv = zt[i][r];
    z_sqf = fmaf(zv, zv, z_sqf);
#pragma unroll
    for (int u = 0; u < 8; ++u) {
      const float d = zv - cqT[i][cg + 8 * u];
      dsq[u] = fmaf(d, d, dsq[u]);
    }
  }
  float lin[8];
#pragma unroll
  for (int u = 0; u < 8; ++u) lin[u] = slin[r][cg + 8 * u];

  const double EPS = 0.001;
  const double SQRTK = sqrt(128.0);
  const double z_sq = (double)z_sqf;
  double tau = SQRTK * fmax(1.0 - z_sq, 0.001) * 0.5;
  tau = fmax(tau, 0.01);
  const double inv_tau = 1.0 / tau;
  const double r2 = fmin(z_sq, 1.0 - EPS);
  const double lam_fac = (1.0 - r2 + EPS) * 0.5 / SQRTK;  // (1/lam)/sqrt(K)
  const double* __restrict__ csqd = (const double*)(ws + WS_CSQ);

  double sc[8];
#pragma unroll
  for (int u = 0; u < 8; ++u) {
    const int n = cg + 8 * u;
    const double c_sq = csqd[n];
    const double denom = (1.0 - z_sq) * (1.0 - c_sq);
    // R12: shifted-form arccosh in f32. d = arg-1 >= 0; clamp d to EPS
    // (== ref's arg = max(arg, 1+EPS)); all f32 operands positive.
    float df = 2.0f * dsq[u] / ((float)denom + 0.001f);
    df = fmaxf(df, 0.001f);
    const float root = sqrtf(df * (df + 2.0f));
    const float dist = log1pf(df + root);               // == arccosh(1+d)
    sc[u] = -(double)dist * inv_tau + (double)lin[u] * lam_fac;
  }
  __syncthreads();  // all cqT/zt/slin reads done before s_exp overlay

  // per-thread max (n increasing -> strict '>' keeps lowest index)
  {
    double mx = sc[0];
    int am = cg;
#pragma unroll
    for (int u = 1; u < 8; ++u)
      if (sc[u] > mx) { mx = sc[u]; am = cg + 8 * u; }
    pmax[r][cg] = mx;
    parg[r][cg] = am;
  }
  __syncthreads();
  if (t < 32) {
    double m = pmax[t][0];
    int a = parg[t][0];
#pragma unroll
    for (int g = 1; g < 8; ++g) {
      const double v = pmax[t][g];
      const int aa = parg[t][g];
      if (v > m || (v == m && aa < a)) { m = v; a = aa; }
    }
    rowmax[t] = m;
    rowarg[t] = a;
  }
  __syncthreads();
  {
    const double m = rowmax[r];
    double ps = 0.0;
#pragma unroll
    for (int u = 0; u < 8; ++u) {
      // R12: f32 exp after fp64 max-subtraction (arg <= 0, no overflow)
      const double e = (double)expf((float)(sc[u] - m));
      s_exp[r][cg + 8 * u] = e;
      ps += e;
    }
    pmax[r][cg] = ps;
  }
  __syncthreads();
  if (t < 32) {
    double s = 0.0;
#pragma unroll
    for (int g = 0; g < 8; ++g) s += pmax[t][g];
    rowinv[t] = 1.0 / s;
  }
  __syncthreads();
  for (int idx = t; idx < 2048; idx += 256) {
    const int b = idx >> 6, n = idx & 63;
    out[(size_t)(b0 + b) * 64 + n] = (float)(s_exp[b][n] * rowinv[b]);
  }
  if (t < 32) out[(size_t)B_TOT * 64 + b0 + t] = (float)rowarg[t];
}

extern "C" void kernel_launch(void* const* d_in, const int* in_sizes, int n_in,
                              void* d_out, int out_size, void* d_ws, size_t ws_size,
                              hipStream_t stream) {
  const float* z = (const float*)d_in[0];
  const float* feat = (const float*)d_in[1];
  const float* qzw = (const float*)d_in[2];
  const float* qzb = (const float*)d_in[3];
  const float* qfw = (const float*)d_in[4];
  const float* qfb = (const float*)d_in[5];
  const float* gamma = (const float*)d_in[6];
  const float* cq = (const float*)d_in[7];
  float* out = (float*)d_out;
  char* ws = (char*)d_ws;  // requires ws_size >= 6033408

  prep_s<<<dim3(256), dim3(256), 0, stream>>>(gamma, cq, ws);
  prep_pack<<<dim3(256), dim3(256), 0, stream>>>(qfw, cq, qzw, qzb, qfb, ws);
  gemm_tail_kernel<<<dim3(B_TOT / 32), dim3(256), 0, stream>>>(z, feat, cq, ws, out);
}

// Round 17
// 134.444 us; speedup vs baseline: 1.0032x; 1.0032x over previous
//
#include <hip/hip_runtime.h>
#include <hip/hip_bf16.h>
#include <cmath>
#include <cstring>

#define B_TOT 16384

typedef unsigned int uint_t;
typedef unsigned short ushort_t;
typedef __attribute__((ext_vector_type(8))) short bf16x8;
typedef __attribute__((ext_vector_type(16))) float f32x16;

// workspace layout (bytes); total 6033408 (~5.76 MiB)
#define WS_TAB 0          // uint32[192]
#define WS_CSQ 1024       // double[64]
#define WS_LIN 4096       // float[16384][64] = 4 MiB (UNUSED after R9 fusion)
#define WS_S   4198400    // float[64][4096] = 1 MiB (prep_s -> prep_pack)
#define WS_PPK 5246976    // A-packs: 192 steps * 4 KiB = 786432
// pack frag addr: ((s*4 + mt*2 + plane)*64 + lane)*16 ; plane 0=hi 1=lo
// lane (r=lane&31,h=lane>>5) holds P[n=mt*32+r][kappa = s*16 + h*8 + e]

// ---------- prep 1: S[n][cell] = sum_k cq[n,k]*gamma[k][cell] (LDS-staged) ----
__global__ __launch_bounds__(256) void prep_s(const float* __restrict__ g,
                                              const float* __restrict__ cq,
                                              char* __restrict__ ws) {
  __shared__ float gl[128][68];
  __shared__ float cql[16][132];
  float* S = (float*)(ws + WS_S);
  const int ns = blockIdx.x >> 6, J = blockIdx.x & 63, t = threadIdx.x;
  for (int i = t; i < 2048; i += 256) {
    const int k = i >> 4, c4 = (i & 15) * 4;
    *(float4*)&gl[k][c4] = *(const float4*)(g + (size_t)k * 4096 + J * 64 + c4);
  }
  for (int i = t; i < 2048; i += 256) {
    const int n16 = i >> 7, k = i & 127;
    cql[n16][k] = cq[(ns * 16 + n16) * 128 + k];
  }
  __syncthreads();
  const int n16 = t >> 4, c4 = (t & 15) * 4;
  float4 acc = {0.f, 0.f, 0.f, 0.f};
#pragma unroll 8
  for (int k = 0; k < 128; ++k) {
    const float w = cql[n16][k];
    const float4 gv = *(const float4*)&gl[k][c4];
    acc.x = fmaf(w, gv.x, acc.x);
    acc.y = fmaf(w, gv.y, acc.y);
    acc.z = fmaf(w, gv.z, acc.z);
    acc.w = fmaf(w, gv.w, acc.w);
  }
  *(float4*)(S + (size_t)(ns * 16 + n16) * 4096 + J * 64 + c4) = acc;
}

// ---------- prep 2: build bf16 hi/lo A-packs + tab + csq (256 blocks) --------
__global__ __launch_bounds__(256) void prep_pack(
    const float* __restrict__ qfw, const float* __restrict__ cq,
    const float* __restrict__ qzw, const float* __restrict__ qzb,
    const float* __restrict__ qfb, char* __restrict__ ws) {
  __shared__ float Sl[4096];
  __shared__ uint_t tabl[192];
  __shared__ float psumf[128][2];
  const int n = blockIdx.x & 63, part = blockIdx.x >> 6, t = threadIdx.x;
  const float* __restrict__ S = (const float*)(ws + WS_S) + (size_t)n * 4096;
  for (int i = t; i < 4096; i += 256) Sl[i] = S[i];
  if (t < 64) {
    const int i = t;
    const int start = (i < 16) ? 4 * i
                     : (i < 32) ? 64 + 3 * (i - 16)
                     : (i < 48) ? 112 + 2 * (i - 32)
                                : 144 + (i - 48);
    const int nst = 4 - (i >> 4);
    for (int u = 0; u < nst; ++u)
      tabl[start + u] = (0u << 16) | ((uint_t)i << 8) | (uint_t)(16 * ((i >> 4) + u));
  } else if (t < 80) tabl[160 + (t - 64)] = (1u << 16) | (uint_t)((t - 64) * 16);
  else if (t < 84)   tabl[176 + (t - 80)] = (2u << 16) | (uint_t)((t - 80) * 16);
  else if (t == 84)  tabl[180] = (3u << 16);
  else if (t < 96)   tabl[181 + (t - 85)] = 0;
  __syncthreads();
  if (part == 0 && n == 0 && t < 192) ((uint_t*)(ws + WS_TAB))[t] = tabl[t];

  const int mt = n >> 5, r = n & 31;
  auto wpack = [&](int s, int jo, float val) {
    const __hip_bfloat16 hb = __float2bfloat16(val);
    const float hf = __bfloat162float(hb);
    const __hip_bfloat16 lb = __float2bfloat16(val - hf);
    ushort_t hu, lu;
    memcpy(&hu, &hb, 2);
    memcpy(&lu, &lb, 2);
    const size_t base =
        (((size_t)s * 4 + mt * 2) * 64 + ((jo >> 3) & 1) * 32 + r) * 16 + (jo & 7) * 2;
    *(ushort_t*)(ws + WS_PPK + base) = hu;
    *(ushort_t*)(ws + WS_PPK + base + 1024) = lu;
  };

  for (int v = part * 640 + t; v < (part + 1) * 640; v += 256) {
    const int s = v >> 4, jo = v & 15;
    const uint_t inf = tabl[s];
    const int i = (inf >> 8) & 255, j0 = inf & 255;
    const int j = j0 + jo;
    const float val =
        (j < i) ? 0.f : ((j > i) ? Sl[i * 64 + j] + Sl[j * 64 + i] : Sl[i * 64 + i]);
    wpack(s, jo, val);
  }
  const float* __restrict__ cqn = cq + n * 128;

  if (part >= 2) {
    const int fl = t & 127, kh = t >> 7;
    const int f = (part - 2) * 128 + fl;
    float a = 0.f;
#pragma unroll 8
    for (int k = 0; k < 64; ++k)
      a = fmaf(qfw[(kh * 64 + k) * 256 + f], cqn[kh * 64 + k], a);
    psumf[fl][kh] = a;
    __syncthreads();
    if (t < 128) {
      const int ff = (part - 2) * 128 + t;
      wpack(160 + (ff >> 4), ff & 15, psumf[t][0] + psumf[t][1]);
    }
  } else if (part == 1) {
    if (t < 64) {
      float a = 0.f;
#pragma unroll 8
      for (int k = 0; k < 128; ++k) a = fmaf(cqn[k], qzw[k * 64 + t], a);
      wpack(176 + (t >> 4), t & 15, a);
    }
    for (int v2 = t; v2 < 176; v2 += 256) wpack(181 + (v2 >> 4), v2 & 15, 0.f);
  } else {
    if (t == 128) {
      float a = 0.f;
      for (int k = 0; k < 128; ++k) a = fmaf(qzb[k] + qfb[k], cqn[k], a);
      wpack(180, 0, a);
    } else if (t > 128 && t < 144) wpack(180, t - 128, 0.f);
    if (t == 144) {
      double a = 0.0;
      for (int d = 0; d < 64; ++d) a = fma((double)cqn[d], (double)cqn[d], a);
      ((double*)(ws + WS_CSQ))[n] = a;
    }
  }
}

// ---------- fused gemm+tail: 512 blocks x 256 thr (4 waves), 32 rows/block --
// R24 FINAL = R22 = R11-exact (proven best: 133.60 us total, kernel ~51.5
// us, VGPR 80). R16's 4-acc chain split was neutral (134.9, VGPR 104) ->
// reverted per pre-commitment; MFMA latency chains are covered by the
// 2-wave interleave + B-build VALU.
// Session ledger (160.2 -> 133.6 us, -17%): fusion (R3), f32 shifted-
// arccosh tail (R5), serialization cuts (R9: feat-preload, branch-free
// loop, no-atomic per-wave fold), f32 direct-diff dot (R10), depth-2
// register ping-pong (R11). Closed axes (all HW-measured): wave count
// (R4/R8/R12 — 4 waves + long loops is the optimum; more waves lose
// block co-residency or L1 stream locality), tab decode (R7), LDS
// A-staging (R8/R15), prefetch depth 3 (R14), 4-acc split (R16).
// NOT a hardware roofline (VALU 46 / MFMA 13 / HBM 4%): a structure
// floor. Next lever beyond this session: repack quadratic A-packs to
// drop ~19% structural zeros (rewrites both preps; est. -5 us).
__global__ __launch_bounds__(256, 4) void gemm_tail_kernel(
    const float* __restrict__ z, const float* __restrict__ feat,
    const float* __restrict__ cq, char* __restrict__ ws,
    float* __restrict__ out) {
  __shared__ __align__(16) unsigned char smem[46208];
  // --- gemm phase ---
  float (*z_lds)[68] = (float (*)[68])(smem);        // 8704 (dead after loop)
  float (*slin)[65] = (float (*)[65])(smem + 8704);  // region 0 (live thru tail)
  // fold regions w=0..3 at byte 8704 + w*8320 (float offset w*2080);
  // regions 1..3 (17024..41984) dead after the sum pass.
  // --- tail phase (overlays regions 1..3) ---
  float (*zt)[33] = (float (*)[33])(smem + 17024);       // 8448 -> 25472
  float (*cqT)[65] = (float (*)[65])(smem + 25472);      // 16640 -> 42112
  double (*s_exp)[65] = (double (*)[65])(smem + 25472);  // overlay cqT ([32] rows)
  double (*pmax)[9] = (double (*)[9])(smem + 42112);     // 2304 -> 44416
  int (*parg)[9] = (int (*)[9])(smem + 44416);           // 1152 -> 45568
  double* rowmax = (double*)(smem + 45568);              // 256 -> 45824
  int* rowarg = (int*)(smem + 45824);                    // 128 -> 45952
  double* rowinv = (double*)(smem + 45952);              // 256 -> 46208

  const int t = threadIdx.x, lane = t & 63;
  const int wv = __builtin_amdgcn_readfirstlane(t >> 6);  // 0..3
  const int b0 = blockIdx.x * 32;
  const int h = lane >> 5, c = lane & 31;

  // feat preload: wave wv's mode-1 steps are s = 160+4m+wv, m=0..3.
  float4 fva[4], fvb[4];
#pragma unroll
  for (int m = 0; m < 4; ++m) {
    const float* __restrict__ fp =
        feat + (size_t)(b0 + c) * 256 + (4 * m + wv) * 16 + h * 8;
    fva[m] = *(const float4*)fp;
    fvb[m] = *(const float4*)(fp + 4);
  }

  for (int i = t; i < 2048; i += 256) z_lds[i >> 6][i & 63] = z[(size_t)b0 * 64 + i];
  if (t < 128) z_lds[t >> 2][64 + (t & 3)] = 0.f;
  __syncthreads();

  const bf16x8* __restrict__ pp = (const bf16x8*)(ws + WS_PPK);
  f32x16 acc[2] = {};

  // RNE hi/lo split + 6 MFMAs for step with A-frags passed in registers
  auto do_step = [&](const float* xv, bf16x8 Ah0, bf16x8 Al0, bf16x8 Ah1,
                     bf16x8 Al1) {
    uint_t bhw[4], blw[4];
#pragma unroll
    for (int e2 = 0; e2 < 4; ++e2) {
      const float2 xp = {xv[2 * e2], xv[2 * e2 + 1]};
      const __hip_bfloat162 hb2 = __float22bfloat162_rn(xp);
      uint_t hw;
      memcpy(&hw, &hb2, 4);
      const float h0 = __uint_as_float(hw << 16);
      const float h1 = __uint_as_float(hw & 0xffff0000u);
      const float2 lp = {xp.x - h0, xp.y - h1};
      const __hip_bfloat162 lb2 = __float22bfloat162_rn(lp);
      uint_t lw;
      memcpy(&lw, &lb2, 4);
      bhw[e2] = hw;
      blw[e2] = lw;
    }
    bf16x8 Bh, Bl;
    memcpy(&Bh, bhw, 16);
    memcpy(&Bl, blw, 16);
    acc[0] = __builtin_amdgcn_mfma_f32_32x32x16_bf16(Ah0, Bh, acc[0], 0, 0, 0);
    acc[0] = __builtin_amdgcn_mfma_f32_32x32x16_bf16(Ah0, Bl, acc[0], 0, 0, 0);
    acc[0] = __builtin_amdgcn_mfma_f32_32x32x16_bf16(Al0, Bh, acc[0], 0, 0, 0);
    acc[1] = __builtin_amdgcn_mfma_f32_32x32x16_bf16(Ah1, Bh, acc[1], 0, 0, 0);
    acc[1] = __builtin_amdgcn_mfma_f32_32x32x16_bf16(Ah1, Bl, acc[1], 0, 0, 0);
    acc[1] = __builtin_amdgcn_mfma_f32_32x32x16_bf16(Al1, Bh, acc[1], 0, 0, 0);
  };

  // mode-0 B build for step s (branch-free decode, LDS reads)
  auto build_xv0 = [&](int s, float* xv) {
    int i_idx, p0;
    if (s < 64) {
      i_idx = s >> 2; p0 = (s & 3) * 16;
    } else if (s < 112) {
      const int q = s - 64, d = (q * 86) >> 8;  // d = q/3 exact for q<48
      i_idx = 16 + d; p0 = (q - 3 * d + 1) * 16;
    } else if (s < 144) {
      const int q = s - 112;
      i_idx = 32 + (q >> 1); p0 = ((q & 1) + 2) * 16;
    } else {
      i_idx = s - 96; p0 = 48;
    }
    const float zi = z_lds[c][i_idx];
    const float* __restrict__ zp = &z_lds[c][p0 + h * 8];
    const float4 a = *(const float4*)zp, b2 = *(const float4*)(zp + 4);
    xv[0] = zi * a.x; xv[1] = zi * a.y; xv[2] = zi * a.z; xv[3] = zi * a.w;
    xv[4] = zi * b2.x; xv[5] = zi * b2.y; xv[6] = zi * b2.z; xv[7] = zi * b2.w;
  };

  // R11 main loop: 40 mode-0 steps as 20 depth-2 ping-pong pairs.
  // pA_ holds step sA = wv+8*p; pB_ holds sB = sA+4.
  bf16x8 pA0, pA1, pA2, pA3, pB0, pB1, pB2, pB3;
  {
    const size_t b4 = (size_t)wv * 256;  // step wv * 4 frags * 64 lanes
    pA0 = pp[b4 + lane]; pA1 = pp[b4 + 64 + lane];
    pA2 = pp[b4 + 128 + lane]; pA3 = pp[b4 + 192 + lane];
  }
#pragma unroll 2
  for (int p = 0; p < 20; ++p) {
    const int sA = wv + p * 8, sB = sA + 4;
    {  // issue loads for sB (consumed after compute(sA))
      const size_t b4 = (size_t)sB * 256;
      pB0 = pp[b4 + lane]; pB1 = pp[b4 + 64 + lane];
      pB2 = pp[b4 + 128 + lane]; pB3 = pp[b4 + 192 + lane];
    }
    {
      float xv[8];
      build_xv0(sA, xv);
      do_step(xv, pA0, pA1, pA2, pA3);
    }
    if (p < 19) {  // issue loads for next pair's sA (consumed after compute(sB))
      const size_t b4 = (size_t)(sA + 8) * 256;
      pA0 = pp[b4 + lane]; pA1 = pp[b4 + 64 + lane];
      pA2 = pp[b4 + 128 + lane]; pA3 = pp[b4 + 192 + lane];
    }
    {
      float xv[8];
      build_xv0(sB, xv);
      do_step(xv, pB0, pB1, pB2, pB3);
    }
  }
  // epilogue its 40..45 (A loads direct; latency-light, 6 of 46 steps)
  auto do_mfma_g = [&](const float* xv, int s) {
    const bf16x8 Ah0 = pp[((size_t)s * 4 + 0) * 64 + lane];
    const bf16x8 Al0 = pp[((size_t)s * 4 + 1) * 64 + lane];
    const bf16x8 Ah1 = pp[((size_t)s * 4 + 2) * 64 + lane];
    const bf16x8 Al1 = pp[((size_t)s * 4 + 3) * 64 + lane];
    do_step(xv, Ah0, Al0, Ah1, Al1);
  };
#pragma unroll
  for (int m = 0; m < 4; ++m) {
    const float xv[8] = {fva[m].x, fva[m].y, fva[m].z, fva[m].w,
                         fvb[m].x, fvb[m].y, fvb[m].z, fvb[m].w};
    do_mfma_g(xv, 160 + 4 * m + wv);
  }
  {
    const float* __restrict__ zp = &z_lds[c][wv * 16 + h * 8];
    const float4 a = *(const float4*)zp, b2 = *(const float4*)(zp + 4);
    const float xv[8] = {a.x, a.y, a.z, a.w, b2.x, b2.y, b2.z, b2.w};
    do_mfma_g(xv, 176 + wv);
  }
  {
    const float xv[8] = {(h == 0) ? 1.f : 0.f, 0.f, 0.f, 0.f, 0.f, 0.f, 0.f, 0.f};
    do_mfma_g(xv, 180 + wv);
  }

  // fold: per-wave plain writes (conflict-free; full (c,n) coverage)
  {
    float* __restrict__ slw = (float*)(smem + 8704) + wv * 2080;
#pragma unroll
    for (int mt = 0; mt < 2; ++mt)
#pragma unroll
      for (int r = 0; r < 16; ++r) {
        const int n = mt * 32 + (r & 3) + 8 * (r >> 2) + 4 * h;
        slw[c * 65 + n] = acc[mt][r];
      }
  }
  __syncthreads();
  // sum 4 wave regions into region 0
  for (int idx = t; idx < 2048; idx += 256) {
    const int c0 = idx >> 6, n0 = idx & 63;
    float* __restrict__ base = (float*)(smem + 8704) + c0 * 65 + n0;
    base[0] = (base[0] + base[2080]) + (base[4160] + base[6240]);
  }
  __syncthreads();

  // --- tail staging (overwrites dead regions 1..3) ---
  for (int i = t; i < 2048; i += 256) zt[i & 63][i >> 6] = z[(size_t)b0 * 64 + i];
  for (int i = t; i < 4096; i += 256) {
    const int n = i >> 6, ii = i & 63;
    cqT[ii][n] = cq[n * 128 + ii];
  }
  __syncthreads();

  // --- tail phase ---
  const int r = t & 31, cg = t >> 5;

  // R17: f32 direct-diff dist_sq (reference formulation; no cancellation)
  float z_sqf = 0.f;
  float dsq[8] = {0.f, 0.f, 0.f, 0.f, 0.f, 0.f, 0.f, 0.f};
#pragma unroll 4
  for (int i = 0; i < 64; ++i) {
    const float zv = zt[i][r];
    z_sqf = fmaf(zv, zv, z_sqf);
#pragma unroll
    for (int u = 0; u < 8; ++u) {
      const float d = zv - cqT[i][cg + 8 * u];
      dsq[u] = fmaf(d, d, dsq[u]);
    }
  }
  float lin[8];
#pragma unroll
  for (int u = 0; u < 8; ++u) lin[u] = slin[r][cg + 8 * u];

  const double EPS = 0.001;
  const double SQRTK = sqrt(128.0);
  const double z_sq = (double)z_sqf;
  double tau = SQRTK * fmax(1.0 - z_sq, 0.001) * 0.5;
  tau = fmax(tau, 0.01);
  const double inv_tau = 1.0 / tau;
  const double r2 = fmin(z_sq, 1.0 - EPS);
  const double lam_fac = (1.0 - r2 + EPS) * 0.5 / SQRTK;  // (1/lam)/sqrt(K)
  const double* __restrict__ csqd = (const double*)(ws + WS_CSQ);

  double sc[8];
#pragma unroll
  for (int u = 0; u < 8; ++u) {
    const int n = cg + 8 * u;
    const double c_sq = csqd[n];
    const double denom = (1.0 - z_sq) * (1.0 - c_sq);
    // R12: shifted-form arccosh in f32. d = arg-1 >= 0; clamp d to EPS
    // (== ref's arg = max(arg, 1+EPS)); all f32 operands positive.
    float df = 2.0f * dsq[u] / ((float)denom + 0.001f);
    df = fmaxf(df, 0.001f);
    const float root = sqrtf(df * (df + 2.0f));
    const float dist = log1pf(df + root);               // == arccosh(1+d)
    sc[u] = -(double)dist * inv_tau + (double)lin[u] * lam_fac;
  }
  __syncthreads();  // all cqT/zt/slin reads done before s_exp overlay

  // per-thread max (n increasing -> strict '>' keeps lowest index)
  {
    double mx = sc[0];
    int am = cg;
#pragma unroll
    for (int u = 1; u < 8; ++u)
      if (sc[u] > mx) { mx = sc[u]; am = cg + 8 * u; }
    pmax[r][cg] = mx;
    parg[r][cg] = am;
  }
  __syncthreads();
  if (t < 32) {
    double m = pmax[t][0];
    int a = parg[t][0];
#pragma unroll
    for (int g = 1; g < 8; ++g) {
      const double v = pmax[t][g];
      const int aa = parg[t][g];
      if (v > m || (v == m && aa < a)) { m = v; a = aa; }
    }
    rowmax[t] = m;
    rowarg[t] = a;
  }
  __syncthreads();
  {
    const double m = rowmax[r];
    double ps = 0.0;
#pragma unroll
    for (int u = 0; u < 8; ++u) {
      // R12: f32 exp after fp64 max-subtraction (arg <= 0, no overflow)
      const double e = (double)expf((float)(sc[u] - m));
      s_exp[r][cg + 8 * u] = e;
      ps += e;
    }
    pmax[r][cg] = ps;
  }
  __syncthreads();
  if (t < 32) {
    double s = 0.0;
#pragma unroll
    for (int g = 0; g < 8; ++g) s += pmax[t][g];
    rowinv[t] = 1.0 / s;
  }
  __syncthreads();
  for (int idx = t; idx < 2048; idx += 256) {
    const int b = idx >> 6, n = idx & 63;
    out[(size_t)(b0 + b) * 64 + n] = (float)(s_exp[b][n] * rowinv[b]);
  }
  if (t < 32) out[(size_t)B_TOT * 64 + b0 + t] = (float)rowarg[t];
}

extern "C" void kernel_launch(void* const* d_in, const int* in_sizes, int n_in,
                              void* d_out, int out_size, void* d_ws, size_t ws_size,
                              hipStream_t stream) {
  const float* z = (const float*)d_in[0];
  const float* feat = (const float*)d_in[1];
  const float* qzw = (const float*)d_in[2];
  const float* qzb = (const float*)d_in[3];
  const float* qfw = (const float*)d_in[4];
  const float* qfb = (const float*)d_in[5];
  const float* gamma = (const float*)d_in[6];
  const float* cq = (const float*)d_in[7];
  float* out = (float*)d_out;
  char* ws = (char*)d_ws;  // requires ws_size >= 6033408

  prep_s<<<dim3(256), dim3(256), 0, stream>>>(gamma, cq, ws);
  prep_pack<<<dim3(256), dim3(256), 0, stream>>>(qfw, cq, qzw, qzb, qfb, ws);
  gemm_tail_kernel<<<dim3(B_TOT / 32), dim3(256), 0, stream>>>(z, feat, cq, ws, out);
}

// Round 18
// 133.063 us; speedup vs baseline: 1.0136x; 1.0104x over previous
//
#include <hip/hip_runtime.h>
#include <hip/hip_bf16.h>
#include <cmath>
#include <cstring>

#define B_TOT 16384

typedef unsigned int uint_t;
typedef unsigned short ushort_t;
typedef __attribute__((ext_vector_type(8))) short bf16x8;
typedef __attribute__((ext_vector_type(16))) float f32x16;

// workspace layout (bytes); total 6033408 (~5.76 MiB)
#define WS_TAB 0          // uint32[192]
#define WS_CSQ 1024       // double[64]
#define WS_LIN 4096       // float[16384][64] = 4 MiB (UNUSED after R9 fusion)
#define WS_S   4198400    // float[64][4096] = 1 MiB (prep_s -> prep_pack)
#define WS_PPK 5246976    // A-packs: 192 steps * 4 KiB = 786432
// pack frag addr: ((s*4 + mt*2 + plane)*64 + lane)*16 ; plane 0=hi 1=lo
// lane (r=lane&31,h=lane>>5) holds P[n=mt*32+r][kappa = s*16 + h*8 + e]

// ---------- prep 1: S[n][cell] = sum_k cq[n,k]*gamma[k][cell] (LDS-staged) ----
__global__ __launch_bounds__(256) void prep_s(const float* __restrict__ g,
                                              const float* __restrict__ cq,
                                              char* __restrict__ ws) {
  __shared__ float gl[128][68];
  __shared__ float cql[16][132];
  float* S = (float*)(ws + WS_S);
  const int ns = blockIdx.x >> 6, J = blockIdx.x & 63, t = threadIdx.x;
  for (int i = t; i < 2048; i += 256) {
    const int k = i >> 4, c4 = (i & 15) * 4;
    *(float4*)&gl[k][c4] = *(const float4*)(g + (size_t)k * 4096 + J * 64 + c4);
  }
  for (int i = t; i < 2048; i += 256) {
    const int n16 = i >> 7, k = i & 127;
    cql[n16][k] = cq[(ns * 16 + n16) * 128 + k];
  }
  __syncthreads();
  const int n16 = t >> 4, c4 = (t & 15) * 4;
  float4 acc = {0.f, 0.f, 0.f, 0.f};
#pragma unroll 8
  for (int k = 0; k < 128; ++k) {
    const float w = cql[n16][k];
    const float4 gv = *(const float4*)&gl[k][c4];
    acc.x = fmaf(w, gv.x, acc.x);
    acc.y = fmaf(w, gv.y, acc.y);
    acc.z = fmaf(w, gv.z, acc.z);
    acc.w = fmaf(w, gv.w, acc.w);
  }
  *(float4*)(S + (size_t)(ns * 16 + n16) * 4096 + J * 64 + c4) = acc;
}

// ---------- prep 2: build bf16 hi/lo A-packs + tab + csq (256 blocks) --------
__global__ __launch_bounds__(256) void prep_pack(
    const float* __restrict__ qfw, const float* __restrict__ cq,
    const float* __restrict__ qzw, const float* __restrict__ qzb,
    const float* __restrict__ qfb, char* __restrict__ ws) {
  __shared__ float Sl[4096];
  __shared__ uint_t tabl[192];
  __shared__ float psumf[128][2];
  const int n = blockIdx.x & 63, part = blockIdx.x >> 6, t = threadIdx.x;
  const float* __restrict__ S = (const float*)(ws + WS_S) + (size_t)n * 4096;
  for (int i = t; i < 4096; i += 256) Sl[i] = S[i];
  if (t < 64) {
    const int i = t;
    const int start = (i < 16) ? 4 * i
                     : (i < 32) ? 64 + 3 * (i - 16)
                     : (i < 48) ? 112 + 2 * (i - 32)
                                : 144 + (i - 48);
    const int nst = 4 - (i >> 4);
    for (int u = 0; u < nst; ++u)
      tabl[start + u] = (0u << 16) | ((uint_t)i << 8) | (uint_t)(16 * ((i >> 4) + u));
  } else if (t < 80) tabl[160 + (t - 64)] = (1u << 16) | (uint_t)((t - 64) * 16);
  else if (t < 84)   tabl[176 + (t - 80)] = (2u << 16) | (uint_t)((t - 80) * 16);
  else if (t == 84)  tabl[180] = (3u << 16);
  else if (t < 96)   tabl[181 + (t - 85)] = 0;
  __syncthreads();
  if (part == 0 && n == 0 && t < 192) ((uint_t*)(ws + WS_TAB))[t] = tabl[t];

  const int mt = n >> 5, r = n & 31;
  auto wpack = [&](int s, int jo, float val) {
    const __hip_bfloat16 hb = __float2bfloat16(val);
    const float hf = __bfloat162float(hb);
    const __hip_bfloat16 lb = __float2bfloat16(val - hf);
    ushort_t hu, lu;
    memcpy(&hu, &hb, 2);
    memcpy(&lu, &lb, 2);
    const size_t base =
        (((size_t)s * 4 + mt * 2) * 64 + ((jo >> 3) & 1) * 32 + r) * 16 + (jo & 7) * 2;
    *(ushort_t*)(ws + WS_PPK + base) = hu;
    *(ushort_t*)(ws + WS_PPK + base + 1024) = lu;
  };

  for (int v = part * 640 + t; v < (part + 1) * 640; v += 256) {
    const int s = v >> 4, jo = v & 15;
    const uint_t inf = tabl[s];
    const int i = (inf >> 8) & 255, j0 = inf & 255;
    const int j = j0 + jo;
    const float val =
        (j < i) ? 0.f : ((j > i) ? Sl[i * 64 + j] + Sl[j * 64 + i] : Sl[i * 64 + i]);
    wpack(s, jo, val);
  }
  const float* __restrict__ cqn = cq + n * 128;

  if (part >= 2) {
    const int fl = t & 127, kh = t >> 7;
    const int f = (part - 2) * 128 + fl;
    float a = 0.f;
#pragma unroll 8
    for (int k = 0; k < 64; ++k)
      a = fmaf(qfw[(kh * 64 + k) * 256 + f], cqn[kh * 64 + k], a);
    psumf[fl][kh] = a;
    __syncthreads();
    if (t < 128) {
      const int ff = (part - 2) * 128 + t;
      wpack(160 + (ff >> 4), ff & 15, psumf[t][0] + psumf[t][1]);
    }
  } else if (part == 1) {
    if (t < 64) {
      float a = 0.f;
#pragma unroll 8
      for (int k = 0; k < 128; ++k) a = fmaf(cqn[k], qzw[k * 64 + t], a);
      wpack(176 + (t >> 4), t & 15, a);
    }
    for (int v2 = t; v2 < 176; v2 += 256) wpack(181 + (v2 >> 4), v2 & 15, 0.f);
  } else {
    if (t == 128) {
      float a = 0.f;
      for (int k = 0; k < 128; ++k) a = fmaf(qzb[k] + qfb[k], cqn[k], a);
      wpack(180, 0, a);
    } else if (t > 128 && t < 144) wpack(180, t - 128, 0.f);
    if (t == 144) {
      double a = 0.0;
      for (int d = 0; d < 64; ++d) a = fma((double)cqn[d], (double)cqn[d], a);
      ((double*)(ws + WS_CSQ))[n] = a;
    }
  }
}

// ---------- fused gemm+tail: 512 blocks x 256 thr (4 waves), 32 rows/block --
// R25: single change vs R22 — B-side raw-input prefetch. A-packs are
// ping-pong-prefetched (R11 ✓), but the B-build LDS reads (zi + 2x
// ds_read_b128, ~120cy) were issued at consumption behind a RUNTIME
// decode (p is runtime under unroll 2 -> compiler can't hoist across the
// MFMA cluster). Now raw B inputs (9 floats) for step s+1 are read during
// step s's build+MFMA phase, mirroring the A-side ping-pong. Named
// buffers (rule #20); +18 VGPR -> ~98 < 128 cap.
// Kept: R9 cuts, R11 A-ping-pong, R12/R17 f32 tail. Closed axes: wave
// count (R4/R8/R12), tab (R7), LDS A-staging (R8/R15), depth-3 (R14),
// 4-acc (R16).
__global__ __launch_bounds__(256, 4) void gemm_tail_kernel(
    const float* __restrict__ z, const float* __restrict__ feat,
    const float* __restrict__ cq, char* __restrict__ ws,
    float* __restrict__ out) {
  __shared__ __align__(16) unsigned char smem[46208];
  // --- gemm phase ---
  float (*z_lds)[68] = (float (*)[68])(smem);        // 8704 (dead after loop)
  float (*slin)[65] = (float (*)[65])(smem + 8704);  // region 0 (live thru tail)
  // fold regions w=0..3 at byte 8704 + w*8320 (float offset w*2080);
  // regions 1..3 (17024..41984) dead after the sum pass.
  // --- tail phase (overlays regions 1..3) ---
  float (*zt)[33] = (float (*)[33])(smem + 17024);       // 8448 -> 25472
  float (*cqT)[65] = (float (*)[65])(smem + 25472);      // 16640 -> 42112
  double (*s_exp)[65] = (double (*)[65])(smem + 25472);  // overlay cqT ([32] rows)
  double (*pmax)[9] = (double (*)[9])(smem + 42112);     // 2304 -> 44416
  int (*parg)[9] = (int (*)[9])(smem + 44416);           // 1152 -> 45568
  double* rowmax = (double*)(smem + 45568);              // 256 -> 45824
  int* rowarg = (int*)(smem + 45824);                    // 128 -> 45952
  double* rowinv = (double*)(smem + 45952);              // 256 -> 46208

  const int t = threadIdx.x, lane = t & 63;
  const int wv = __builtin_amdgcn_readfirstlane(t >> 6);  // 0..3
  const int b0 = blockIdx.x * 32;
  const int h = lane >> 5, c = lane & 31;

  // feat preload: wave wv's mode-1 steps are s = 160+4m+wv, m=0..3.
  float4 fva[4], fvb[4];
#pragma unroll
  for (int m = 0; m < 4; ++m) {
    const float* __restrict__ fp =
        feat + (size_t)(b0 + c) * 256 + (4 * m + wv) * 16 + h * 8;
    fva[m] = *(const float4*)fp;
    fvb[m] = *(const float4*)(fp + 4);
  }

  for (int i = t; i < 2048; i += 256) z_lds[i >> 6][i & 63] = z[(size_t)b0 * 64 + i];
  if (t < 128) z_lds[t >> 2][64 + (t & 3)] = 0.f;
  __syncthreads();

  const bf16x8* __restrict__ pp = (const bf16x8*)(ws + WS_PPK);
  f32x16 acc[2] = {};

  // RNE hi/lo split + 6 MFMAs for step with A-frags passed in registers
  auto do_step = [&](const float* xv, bf16x8 Ah0, bf16x8 Al0, bf16x8 Ah1,
                     bf16x8 Al1) {
    uint_t bhw[4], blw[4];
#pragma unroll
    for (int e2 = 0; e2 < 4; ++e2) {
      const float2 xp = {xv[2 * e2], xv[2 * e2 + 1]};
      const __hip_bfloat162 hb2 = __float22bfloat162_rn(xp);
      uint_t hw;
      memcpy(&hw, &hb2, 4);
      const float h0 = __uint_as_float(hw << 16);
      const float h1 = __uint_as_float(hw & 0xffff0000u);
      const float2 lp = {xp.x - h0, xp.y - h1};
      const __hip_bfloat162 lb2 = __float22bfloat162_rn(lp);
      uint_t lw;
      memcpy(&lw, &lb2, 4);
      bhw[e2] = hw;
      blw[e2] = lw;
    }
    bf16x8 Bh, Bl;
    memcpy(&Bh, bhw, 16);
    memcpy(&Bl, blw, 16);
    acc[0] = __builtin_amdgcn_mfma_f32_32x32x16_bf16(Ah0, Bh, acc[0], 0, 0, 0);
    acc[0] = __builtin_amdgcn_mfma_f32_32x32x16_bf16(Ah0, Bl, acc[0], 0, 0, 0);
    acc[0] = __builtin_amdgcn_mfma_f32_32x32x16_bf16(Al0, Bh, acc[0], 0, 0, 0);
    acc[1] = __builtin_amdgcn_mfma_f32_32x32x16_bf16(Ah1, Bh, acc[1], 0, 0, 0);
    acc[1] = __builtin_amdgcn_mfma_f32_32x32x16_bf16(Ah1, Bl, acc[1], 0, 0, 0);
    acc[1] = __builtin_amdgcn_mfma_f32_32x32x16_bf16(Al1, Bh, acc[1], 0, 0, 0);
  };

  // R25: raw B-input read for mode-0 step s (decode + LDS reads only)
  auto read_raw = [&](int s, float& zi, float4& ra, float4& rb) {
    int i_idx, p0;
    if (s < 64) {
      i_idx = s >> 2; p0 = (s & 3) * 16;
    } else if (s < 112) {
      const int q = s - 64, d = (q * 86) >> 8;  // d = q/3 exact for q<48
      i_idx = 16 + d; p0 = (q - 3 * d + 1) * 16;
    } else if (s < 144) {
      const int q = s - 112;
      i_idx = 32 + (q >> 1); p0 = ((q & 1) + 2) * 16;
    } else {
      i_idx = s - 96; p0 = 48;
    }
    zi = z_lds[c][i_idx];
    const float* __restrict__ zp = &z_lds[c][p0 + h * 8];
    ra = *(const float4*)zp;
    rb = *(const float4*)(zp + 4);
  };
  auto build_from_raw = [&](float zi, const float4& ra, const float4& rb,
                            float* xv) {
    xv[0] = zi * ra.x; xv[1] = zi * ra.y; xv[2] = zi * ra.z; xv[3] = zi * ra.w;
    xv[4] = zi * rb.x; xv[5] = zi * rb.y; xv[6] = zi * rb.z; xv[7] = zi * rb.w;
  };

  // main loop: 40 mode-0 steps as 20 depth-2 ping-pong pairs; BOTH the
  // A-packs (global) and raw B inputs (LDS) are prefetched one step ahead.
  bf16x8 pA0, pA1, pA2, pA3, pB0, pB1, pB2, pB3;
  float ziA, ziB;
  float4 rA1, rA2, rB1, rB2;
  {
    const size_t b4 = (size_t)wv * 256;  // step wv * 4 frags * 64 lanes
    pA0 = pp[b4 + lane]; pA1 = pp[b4 + 64 + lane];
    pA2 = pp[b4 + 128 + lane]; pA3 = pp[b4 + 192 + lane];
  }
  read_raw(wv, ziA, rA1, rA2);
#pragma unroll 2
  for (int p = 0; p < 20; ++p) {
    const int sA = wv + p * 8, sB = sA + 4;
    {  // issue A-pack loads + raw-B reads for sB
      const size_t b4 = (size_t)sB * 256;
      pB0 = pp[b4 + lane]; pB1 = pp[b4 + 64 + lane];
      pB2 = pp[b4 + 128 + lane]; pB3 = pp[b4 + 192 + lane];
      read_raw(sB, ziB, rB1, rB2);
    }
    {
      float xv[8];
      build_from_raw(ziA, rA1, rA2, xv);
      do_step(xv, pA0, pA1, pA2, pA3);
    }
    if (p < 19) {  // issue loads + raw reads for next pair's sA
      const size_t b4 = (size_t)(sA + 8) * 256;
      pA0 = pp[b4 + lane]; pA1 = pp[b4 + 64 + lane];
      pA2 = pp[b4 + 128 + lane]; pA3 = pp[b4 + 192 + lane];
      read_raw(sA + 8, ziA, rA1, rA2);
    }
    {
      float xv[8];
      build_from_raw(ziB, rB1, rB2, xv);
      do_step(xv, pB0, pB1, pB2, pB3);
    }
  }
  // epilogue its 40..45 (A loads direct; latency-light, 6 of 46 steps)
  auto do_mfma_g = [&](const float* xv, int s) {
    const bf16x8 Ah0 = pp[((size_t)s * 4 + 0) * 64 + lane];
    const bf16x8 Al0 = pp[((size_t)s * 4 + 1) * 64 + lane];
    const bf16x8 Ah1 = pp[((size_t)s * 4 + 2) * 64 + lane];
    const bf16x8 Al1 = pp[((size_t)s * 4 + 3) * 64 + lane];
    do_step(xv, Ah0, Al0, Ah1, Al1);
  };
#pragma unroll
  for (int m = 0; m < 4; ++m) {
    const float xv[8] = {fva[m].x, fva[m].y, fva[m].z, fva[m].w,
                         fvb[m].x, fvb[m].y, fvb[m].z, fvb[m].w};
    do_mfma_g(xv, 160 + 4 * m + wv);
  }
  {
    const float* __restrict__ zp = &z_lds[c][wv * 16 + h * 8];
    const float4 a = *(const float4*)zp, b2 = *(const float4*)(zp + 4);
    const float xv[8] = {a.x, a.y, a.z, a.w, b2.x, b2.y, b2.z, b2.w};
    do_mfma_g(xv, 176 + wv);
  }
  {
    const float xv[8] = {(h == 0) ? 1.f : 0.f, 0.f, 0.f, 0.f, 0.f, 0.f, 0.f, 0.f};
    do_mfma_g(xv, 180 + wv);
  }

  // fold: per-wave plain writes (conflict-free; full (c,n) coverage)
  {
    float* __restrict__ slw = (float*)(smem + 8704) + wv * 2080;
#pragma unroll
    for (int mt = 0; mt < 2; ++mt)
#pragma unroll
      for (int r = 0; r < 16; ++r) {
        const int n = mt * 32 + (r & 3) + 8 * (r >> 2) + 4 * h;
        slw[c * 65 + n] = acc[mt][r];
      }
  }
  __syncthreads();
  // sum 4 wave regions into region 0
  for (int idx = t; idx < 2048; idx += 256) {
    const int c0 = idx >> 6, n0 = idx & 63;
    float* __restrict__ base = (float*)(smem + 8704) + c0 * 65 + n0;
    base[0] = (base[0] + base[2080]) + (base[4160] + base[6240]);
  }
  __syncthreads();

  // --- tail staging (overwrites dead regions 1..3) ---
  for (int i = t; i < 2048; i += 256) zt[i & 63][i >> 6] = z[(size_t)b0 * 64 + i];
  for (int i = t; i < 4096; i += 256) {
    const int n = i >> 6, ii = i & 63;
    cqT[ii][n] = cq[n * 128 + ii];
  }
  __syncthreads();

  // --- tail phase ---
  const int r = t & 31, cg = t >> 5;

  // R17: f32 direct-diff dist_sq (reference formulation; no cancellation)
  float z_sqf = 0.f;
  float dsq[8] = {0.f, 0.f, 0.f, 0.f, 0.f, 0.f, 0.f, 0.f};
#pragma unroll 4
  for (int i = 0; i < 64; ++i) {
    const float zv = zt[i][r];
    z_sqf = fmaf(zv, zv, z_sqf);
#pragma unroll
    for (int u = 0; u < 8; ++u) {
      const float d = zv - cqT[i][cg + 8 * u];
      dsq[u] = fmaf(d, d, dsq[u]);
    }
  }
  float lin[8];
#pragma unroll
  for (int u = 0; u < 8; ++u) lin[u] = slin[r][cg + 8 * u];

  const double EPS = 0.001;
  const double SQRTK = sqrt(128.0);
  const double z_sq = (double)z_sqf;
  double tau = SQRTK * fmax(1.0 - z_sq, 0.001) * 0.5;
  tau = fmax(tau, 0.01);
  const double inv_tau = 1.0 / tau;
  const double r2 = fmin(z_sq, 1.0 - EPS);
  const double lam_fac = (1.0 - r2 + EPS) * 0.5 / SQRTK;  // (1/lam)/sqrt(K)
  const double* __restrict__ csqd = (const double*)(ws + WS_CSQ);

  double sc[8];
#pragma unroll
  for (int u = 0; u < 8; ++u) {
    const int n = cg + 8 * u;
    const double c_sq = csqd[n];
    const double denom = (1.0 - z_sq) * (1.0 - c_sq);
    // R12: shifted-form arccosh in f32. d = arg-1 >= 0; clamp d to EPS
    // (== ref's arg = max(arg, 1+EPS)); all f32 operands positive.
    float df = 2.0f * dsq[u] / ((float)denom + 0.001f);
    df = fmaxf(df, 0.001f);
    const float root = sqrtf(df * (df + 2.0f));
    const float dist = log1pf(df + root);               // == arccosh(1+d)
    sc[u] = -(double)dist * inv_tau + (double)lin[u] * lam_fac;
  }
  __syncthreads();  // all cqT/zt/slin reads done before s_exp overlay

  // per-thread max (n increasing -> strict '>' keeps lowest index)
  {
    double mx = sc[0];
    int am = cg;
#pragma unroll
    for (int u = 1; u < 8; ++u)
      if (sc[u] > mx) { mx = sc[u]; am = cg + 8 * u; }
    pmax[r][cg] = mx;
    parg[r][cg] = am;
  }
  __syncthreads();
  if (t < 32) {
    double m = pmax[t][0];
    int a = parg[t][0];
#pragma unroll
    for (int g = 1; g < 8; ++g) {
      const double v = pmax[t][g];
      const int aa = parg[t][g];
      if (v > m || (v == m && aa < a)) { m = v; a = aa; }
    }
    rowmax[t] = m;
    rowarg[t] = a;
  }
  __syncthreads();
  {
    const double m = rowmax[r];
    double ps = 0.0;
#pragma unroll
    for (int u = 0; u < 8; ++u) {
      // R12: f32 exp after fp64 max-subtraction (arg <= 0, no overflow)
      const double e = (double)expf((float)(sc[u] - m));
      s_exp[r][cg + 8 * u] = e;
      ps += e;
    }
    pmax[r][cg] = ps;
  }
  __syncthreads();
  if (t < 32) {
    double s = 0.0;
#pragma unroll
    for (int g = 0; g < 8; ++g) s += pmax[t][g];
    rowinv[t] = 1.0 / s;
  }
  __syncthreads();
  for (int idx = t; idx < 2048; idx += 256) {
    const int b = idx >> 6, n = idx & 63;
    out[(size_t)(b0 + b) * 64 + n] = (float)(s_exp[b][n] * rowinv[b]);
  }
  if (t < 32) out[(size_t)B_TOT * 64 + b0 + t] = (float)rowarg[t];
}

extern "C" void kernel_launch(void* const* d_in, const int* in_sizes, int n_in,
                              void* d_out, int out_size, void* d_ws, size_t ws_size,
                              hipStream_t stream) {
  const float* z = (const float*)d_in[0];
  const float* feat = (const float*)d_in[1];
  const float* qzw = (const float*)d_in[2];
  const float* qzb = (const float*)d_in[3];
  const float* qfw = (const float*)d_in[4];
  const float* qfb = (const float*)d_in[5];
  const float* gamma = (const float*)d_in[6];
  const float* cq = (const float*)d_in[7];
  float* out = (float*)d_out;
  char* ws = (char*)d_ws;  // requires ws_size >= 6033408

  prep_s<<<dim3(256), dim3(256), 0, stream>>>(gamma, cq, ws);
  prep_pack<<<dim3(256), dim3(256), 0, stream>>>(qfw, cq, qzw, qzb, qfb, ws);
  gemm_tail_kernel<<<dim3(B_TOT / 32), dim3(256), 0, stream>>>(z, feat, cq, ws, out);
}

// Round 20
// 130.854 us; speedup vs baseline: 1.0307x; 1.0169x over previous
//
#include <hip/hip_runtime.h>
#include <hip/hip_bf16.h>
#include <cmath>
#include <cstring>

#define B_TOT 16384

typedef unsigned int uint_t;
typedef unsigned short ushort_t;
typedef __attribute__((ext_vector_type(8))) short bf16x8;
typedef __attribute__((ext_vector_type(16))) float f32x16;

// workspace layout (bytes); total 6033408 (~5.76 MiB)
#define WS_TAB 0          // uint32[192]
#define WS_CSQ 1024       // double[64]
#define WS_LIN 4096       // float[16384][64] = 4 MiB (UNUSED after R9 fusion)
#define WS_S   4198400    // float[64][4096] = 1 MiB (prep_s -> prep_pack)
#define WS_PPK 5246976    // A-packs: 192 steps * 4 KiB = 786432
// pack frag addr: ((s*4 + mt*2 + plane)*64 + lane)*16 ; plane 0=hi 1=lo
// lane (r=lane&31,h=lane>>5) holds P[n=mt*32+r][kappa = s*16 + h*8 + e]

// ---------- prep 1: S[n][cell] = sum_k cq[n,k]*gamma[k][cell] (LDS-staged) ----
__global__ __launch_bounds__(256) void prep_s(const float* __restrict__ g,
                                              const float* __restrict__ cq,
                                              char* __restrict__ ws) {
  __shared__ float gl[128][68];
  __shared__ float cql[16][132];
  float* S = (float*)(ws + WS_S);
  const int ns = blockIdx.x >> 6, J = blockIdx.x & 63, t = threadIdx.x;
  for (int i = t; i < 2048; i += 256) {
    const int k = i >> 4, c4 = (i & 15) * 4;
    *(float4*)&gl[k][c4] = *(const float4*)(g + (size_t)k * 4096 + J * 64 + c4);
  }
  for (int i = t; i < 2048; i += 256) {
    const int n16 = i >> 7, k = i & 127;
    cql[n16][k] = cq[(ns * 16 + n16) * 128 + k];
  }
  __syncthreads();
  const int n16 = t >> 4, c4 = (t & 15) * 4;
  float4 acc = {0.f, 0.f, 0.f, 0.f};
#pragma unroll 8
  for (int k = 0; k < 128; ++k) {
    const float w = cql[n16][k];
    const float4 gv = *(const float4*)&gl[k][c4];
    acc.x = fmaf(w, gv.x, acc.x);
    acc.y = fmaf(w, gv.y, acc.y);
    acc.z = fmaf(w, gv.z, acc.z);
    acc.w = fmaf(w, gv.w, acc.w);
  }
  *(float4*)(S + (size_t)(ns * 16 + n16) * 4096 + J * 64 + c4) = acc;
}

// ---------- prep 2: build bf16 hi/lo A-packs + tab + csq (256 blocks) --------
__global__ __launch_bounds__(256) void prep_pack(
    const float* __restrict__ qfw, const float* __restrict__ cq,
    const float* __restrict__ qzw, const float* __restrict__ qzb,
    const float* __restrict__ qfb, char* __restrict__ ws) {
  __shared__ float Sl[4096];
  __shared__ uint_t tabl[192];
  __shared__ float psumf[128][2];
  const int n = blockIdx.x & 63, part = blockIdx.x >> 6, t = threadIdx.x;
  const float* __restrict__ S = (const float*)(ws + WS_S) + (size_t)n * 4096;
  for (int i = t; i < 4096; i += 256) Sl[i] = S[i];
  if (t < 64) {
    const int i = t;
    const int start = (i < 16) ? 4 * i
                     : (i < 32) ? 64 + 3 * (i - 16)
                     : (i < 48) ? 112 + 2 * (i - 32)
                                : 144 + (i - 48);
    const int nst = 4 - (i >> 4);
    for (int u = 0; u < nst; ++u)
      tabl[start + u] = (0u << 16) | ((uint_t)i << 8) | (uint_t)(16 * ((i >> 4) + u));
  } else if (t < 80) tabl[160 + (t - 64)] = (1u << 16) | (uint_t)((t - 64) * 16);
  else if (t < 84)   tabl[176 + (t - 80)] = (2u << 16) | (uint_t)((t - 80) * 16);
  else if (t == 84)  tabl[180] = (3u << 16);
  else if (t < 96)   tabl[181 + (t - 85)] = 0;
  __syncthreads();
  if (part == 0 && n == 0 && t < 192) ((uint_t*)(ws + WS_TAB))[t] = tabl[t];

  const int mt = n >> 5, r = n & 31;
  auto wpack = [&](int s, int jo, float val) {
    const __hip_bfloat16 hb = __float2bfloat16(val);
    const float hf = __bfloat162float(hb);
    const __hip_bfloat16 lb = __float2bfloat16(val - hf);
    ushort_t hu, lu;
    memcpy(&hu, &hb, 2);
    memcpy(&lu, &lb, 2);
    const size_t base =
        (((size_t)s * 4 + mt * 2) * 64 + ((jo >> 3) & 1) * 32 + r) * 16 + (jo & 7) * 2;
    *(ushort_t*)(ws + WS_PPK + base) = hu;
    *(ushort_t*)(ws + WS_PPK + base + 1024) = lu;
  };

  for (int v = part * 640 + t; v < (part + 1) * 640; v += 256) {
    const int s = v >> 4, jo = v & 15;
    const uint_t inf = tabl[s];
    const int i = (inf >> 8) & 255, j0 = inf & 255;
    const int j = j0 + jo;
    const float val =
        (j < i) ? 0.f : ((j > i) ? Sl[i * 64 + j] + Sl[j * 64 + i] : Sl[i * 64 + i]);
    wpack(s, jo, val);
  }
  const float* __restrict__ cqn = cq + n * 128;

  if (part >= 2) {
    const int fl = t & 127, kh = t >> 7;
    const int f = (part - 2) * 128 + fl;
    float a = 0.f;
#pragma unroll 8
    for (int k = 0; k < 64; ++k)
      a = fmaf(qfw[(kh * 64 + k) * 256 + f], cqn[kh * 64 + k], a);
    psumf[fl][kh] = a;
    __syncthreads();
    if (t < 128) {
      const int ff = (part - 2) * 128 + t;
      wpack(160 + (ff >> 4), ff & 15, psumf[t][0] + psumf[t][1]);
    }
  } else if (part == 1) {
    if (t < 64) {
      float a = 0.f;
#pragma unroll 8
      for (int k = 0; k < 128; ++k) a = fmaf(cqn[k], qzw[k * 64 + t], a);
      wpack(176 + (t >> 4), t & 15, a);
    }
    for (int v2 = t; v2 < 176; v2 += 256) wpack(181 + (v2 >> 4), v2 & 15, 0.f);
  } else {
    if (t == 128) {
      float a = 0.f;
      for (int k = 0; k < 128; ++k) a = fmaf(qzb[k] + qfb[k], cqn[k], a);
      wpack(180, 0, a);
    } else if (t > 128 && t < 144) wpack(180, t - 128, 0.f);
    if (t == 144) {
      double a = 0.0;
      for (int d = 0; d < 64; ++d) a = fma((double)cqn[d], (double)cqn[d], a);
      ((double*)(ws + WS_CSQ))[n] = a;
    }
  }
}

// ---------- fused gemm+tail: 512 blocks x 256 thr (4 waves), 32 rows/block --
// R26: single change vs R25 — tail cq gathers vectorized. The dsq loop
// issued 8 scalar ds_read_b32 per iter (cqT[i][cg+8u], stride 8 -> not
// vectorizable) = 512 scalar LDS reads/thread. New layout cqT2[ii][68]
// permuted as word (n&7)*8 + (n>>3): lane (r,cg)'s eight u-values are
// contiguous -> 2x ds_read_b128 per iter (128 total, -75% tail LDS
// instrs). Reads are same-row broadcast, 2-way aliasing (free, m136);
// staging writes 4-way (16 instrs, negligible). Region 16640 -> 17408 B,
// offsets shifted; LDS 46976.
// Kept: R9 cuts, R11 A-ping-pong, R25 B-raw-prefetch, R12/R17 f32 tail.
// Closed axes: wave count (R4/R8/R12), tab (R7), LDS A-staging (R8/R15),
// depth-3 (R14), 4-acc (R16).
// R27 = identical resubmit of R26 (container infra failure, 4th occurrence
// of this signature; R2/R6/R13 precedents all passed on identical resubmit;
// staging map + bounds + overlay fencing re-audited).
__global__ __launch_bounds__(256, 4) void gemm_tail_kernel(
    const float* __restrict__ z, const float* __restrict__ feat,
    const float* __restrict__ cq, char* __restrict__ ws,
    float* __restrict__ out) {
  __shared__ __align__(16) unsigned char smem[46976];
  // --- gemm phase ---
  float (*z_lds)[68] = (float (*)[68])(smem);        // 8704 (dead after loop)
  float (*slin)[65] = (float (*)[65])(smem + 8704);  // region 0 (live thru tail)
  // fold regions w=0..3 at byte 8704 + w*8320 (float offset w*2080);
  // regions 1..3 (17024..41984) dead after the sum pass.
  // --- tail phase (overlays regions 1..3) ---
  float (*zt)[33] = (float (*)[33])(smem + 17024);       // 8448 -> 25472
  float* cqT2f = (float*)(smem + 25472);                 // [64][68] 17408 -> 42880
  double (*s_exp)[65] = (double (*)[65])(smem + 25472);  // overlay cqT2 (16640)
  double (*pmax)[9] = (double (*)[9])(smem + 42880);     // 2304 -> 45184
  int (*parg)[9] = (int (*)[9])(smem + 45184);           // 1152 -> 46336
  double* rowmax = (double*)(smem + 46336);              // 256 -> 46592
  int* rowarg = (int*)(smem + 46592);                    // 128 -> 46720
  double* rowinv = (double*)(smem + 46720);              // 256 -> 46976

  const int t = threadIdx.x, lane = t & 63;
  const int wv = __builtin_amdgcn_readfirstlane(t >> 6);  // 0..3
  const int b0 = blockIdx.x * 32;
  const int h = lane >> 5, c = lane & 31;

  // feat preload: wave wv's mode-1 steps are s = 160+4m+wv, m=0..3.
  float4 fva[4], fvb[4];
#pragma unroll
  for (int m = 0; m < 4; ++m) {
    const float* __restrict__ fp =
        feat + (size_t)(b0 + c) * 256 + (4 * m + wv) * 16 + h * 8;
    fva[m] = *(const float4*)fp;
    fvb[m] = *(const float4*)(fp + 4);
  }

  for (int i = t; i < 2048; i += 256) z_lds[i >> 6][i & 63] = z[(size_t)b0 * 64 + i];
  if (t < 128) z_lds[t >> 2][64 + (t & 3)] = 0.f;
  __syncthreads();

  const bf16x8* __restrict__ pp = (const bf16x8*)(ws + WS_PPK);
  f32x16 acc[2] = {};

  // RNE hi/lo split + 6 MFMAs for step with A-frags passed in registers
  auto do_step = [&](const float* xv, bf16x8 Ah0, bf16x8 Al0, bf16x8 Ah1,
                     bf16x8 Al1) {
    uint_t bhw[4], blw[4];
#pragma unroll
    for (int e2 = 0; e2 < 4; ++e2) {
      const float2 xp = {xv[2 * e2], xv[2 * e2 + 1]};
      const __hip_bfloat162 hb2 = __float22bfloat162_rn(xp);
      uint_t hw;
      memcpy(&hw, &hb2, 4);
      const float h0 = __uint_as_float(hw << 16);
      const float h1 = __uint_as_float(hw & 0xffff0000u);
      const float2 lp = {xp.x - h0, xp.y - h1};
      const __hip_bfloat162 lb2 = __float22bfloat162_rn(lp);
      uint_t lw;
      memcpy(&lw, &lb2, 4);
      bhw[e2] = hw;
      blw[e2] = lw;
    }
    bf16x8 Bh, Bl;
    memcpy(&Bh, bhw, 16);
    memcpy(&Bl, blw, 16);
    acc[0] = __builtin_amdgcn_mfma_f32_32x32x16_bf16(Ah0, Bh, acc[0], 0, 0, 0);
    acc[0] = __builtin_amdgcn_mfma_f32_32x32x16_bf16(Ah0, Bl, acc[0], 0, 0, 0);
    acc[0] = __builtin_amdgcn_mfma_f32_32x32x16_bf16(Al0, Bh, acc[0], 0, 0, 0);
    acc[1] = __builtin_amdgcn_mfma_f32_32x32x16_bf16(Ah1, Bh, acc[1], 0, 0, 0);
    acc[1] = __builtin_amdgcn_mfma_f32_32x32x16_bf16(Ah1, Bl, acc[1], 0, 0, 0);
    acc[1] = __builtin_amdgcn_mfma_f32_32x32x16_bf16(Al1, Bh, acc[1], 0, 0, 0);
  };

  // raw B-input read for mode-0 step s (decode + LDS reads only)
  auto read_raw = [&](int s, float& zi, float4& ra, float4& rb) {
    int i_idx, p0;
    if (s < 64) {
      i_idx = s >> 2; p0 = (s & 3) * 16;
    } else if (s < 112) {
      const int q = s - 64, d = (q * 86) >> 8;  // d = q/3 exact for q<48
      i_idx = 16 + d; p0 = (q - 3 * d + 1) * 16;
    } else if (s < 144) {
      const int q = s - 112;
      i_idx = 32 + (q >> 1); p0 = ((q & 1) + 2) * 16;
    } else {
      i_idx = s - 96; p0 = 48;
    }
    zi = z_lds[c][i_idx];
    const float* __restrict__ zp = &z_lds[c][p0 + h * 8];
    ra = *(const float4*)zp;
    rb = *(const float4*)(zp + 4);
  };
  auto build_from_raw = [&](float zi, const float4& ra, const float4& rb,
                            float* xv) {
    xv[0] = zi * ra.x; xv[1] = zi * ra.y; xv[2] = zi * ra.z; xv[3] = zi * ra.w;
    xv[4] = zi * rb.x; xv[5] = zi * rb.y; xv[6] = zi * rb.z; xv[7] = zi * rb.w;
  };

  // main loop: 40 mode-0 steps as 20 depth-2 ping-pong pairs; BOTH the
  // A-packs (global) and raw B inputs (LDS) are prefetched one step ahead.
  bf16x8 pA0, pA1, pA2, pA3, pB0, pB1, pB2, pB3;
  float ziA, ziB;
  float4 rA1, rA2, rB1, rB2;
  {
    const size_t b4 = (size_t)wv * 256;  // step wv * 4 frags * 64 lanes
    pA0 = pp[b4 + lane]; pA1 = pp[b4 + 64 + lane];
    pA2 = pp[b4 + 128 + lane]; pA3 = pp[b4 + 192 + lane];
  }
  read_raw(wv, ziA, rA1, rA2);
#pragma unroll 2
  for (int p = 0; p < 20; ++p) {
    const int sA = wv + p * 8, sB = sA + 4;
    {  // issue A-pack loads + raw-B reads for sB
      const size_t b4 = (size_t)sB * 256;
      pB0 = pp[b4 + lane]; pB1 = pp[b4 + 64 + lane];
      pB2 = pp[b4 + 128 + lane]; pB3 = pp[b4 + 192 + lane];
      read_raw(sB, ziB, rB1, rB2);
    }
    {
      float xv[8];
      build_from_raw(ziA, rA1, rA2, xv);
      do_step(xv, pA0, pA1, pA2, pA3);
    }
    if (p < 19) {  // issue loads + raw reads for next pair's sA
      const size_t b4 = (size_t)(sA + 8) * 256;
      pA0 = pp[b4 + lane]; pA1 = pp[b4 + 64 + lane];
      pA2 = pp[b4 + 128 + lane]; pA3 = pp[b4 + 192 + lane];
      read_raw(sA + 8, ziA, rA1, rA2);
    }
    {
      float xv[8];
      build_from_raw(ziB, rB1, rB2, xv);
      do_step(xv, pB0, pB1, pB2, pB3);
    }
  }
  // epilogue its 40..45 (A loads direct; latency-light, 6 of 46 steps)
  auto do_mfma_g = [&](const float* xv, int s) {
    const bf16x8 Ah0 = pp[((size_t)s * 4 + 0) * 64 + lane];
    const bf16x8 Al0 = pp[((size_t)s * 4 + 1) * 64 + lane];
    const bf16x8 Ah1 = pp[((size_t)s * 4 + 2) * 64 + lane];
    const bf16x8 Al1 = pp[((size_t)s * 4 + 3) * 64 + lane];
    do_step(xv, Ah0, Al0, Ah1, Al1);
  };
#pragma unroll
  for (int m = 0; m < 4; ++m) {
    const float xv[8] = {fva[m].x, fva[m].y, fva[m].z, fva[m].w,
                         fvb[m].x, fvb[m].y, fvb[m].z, fvb[m].w};
    do_mfma_g(xv, 160 + 4 * m + wv);
  }
  {
    const float* __restrict__ zp = &z_lds[c][wv * 16 + h * 8];
    const float4 a = *(const float4*)zp, b2 = *(const float4*)(zp + 4);
    const float xv[8] = {a.x, a.y, a.z, a.w, b2.x, b2.y, b2.z, b2.w};
    do_mfma_g(xv, 176 + wv);
  }
  {
    const float xv[8] = {(h == 0) ? 1.f : 0.f, 0.f, 0.f, 0.f, 0.f, 0.f, 0.f, 0.f};
    do_mfma_g(xv, 180 + wv);
  }

  // fold: per-wave plain writes (conflict-free; full (c,n) coverage)
  {
    float* __restrict__ slw = (float*)(smem + 8704) + wv * 2080;
#pragma unroll
    for (int mt = 0; mt < 2; ++mt)
#pragma unroll
      for (int r = 0; r < 16; ++r) {
        const int n = mt * 32 + (r & 3) + 8 * (r >> 2) + 4 * h;
        slw[c * 65 + n] = acc[mt][r];
      }
  }
  __syncthreads();
  // sum 4 wave regions into region 0
  for (int idx = t; idx < 2048; idx += 256) {
    const int c0 = idx >> 6, n0 = idx & 63;
    float* __restrict__ base = (float*)(smem + 8704) + c0 * 65 + n0;
    base[0] = (base[0] + base[2080]) + (base[4160] + base[6240]);
  }
  __syncthreads();

  // --- tail staging (overwrites dead regions 1..3) ---
  for (int i = t; i < 2048; i += 256) zt[i & 63][i >> 6] = z[(size_t)b0 * 64 + i];
  // R26: permuted-transposed cq: word (n&7)*8 + (n>>3) of row ii holds
  // cq[n*128+ii]; lane (r,cg) reads words cg*8..cg*8+7 of row i as 2xfloat4
  // = c_{cg+8u}[i] for u=0..7. Global read stays coalesced (ii = i&63).
  for (int i = t; i < 4096; i += 256) {
    const int n = i >> 6, ii = i & 63;
    cqT2f[ii * 68 + (n & 7) * 8 + (n >> 3)] = cq[n * 128 + ii];
  }
  __syncthreads();

  // --- tail phase ---
  const int r = t & 31, cg = t >> 5;

  // R17 direct-diff dist_sq; R26 vectorized cq gathers (2x b128 per iter)
  float z_sqf = 0.f;
  float dsq[8] = {0.f, 0.f, 0.f, 0.f, 0.f, 0.f, 0.f, 0.f};
#pragma unroll 4
  for (int i = 0; i < 64; ++i) {
    const float zv = zt[i][r];
    z_sqf = fmaf(zv, zv, z_sqf);
    const float* __restrict__ cp = &cqT2f[i * 68 + cg * 8];
    const float4 ca = *(const float4*)cp;
    const float4 cb = *(const float4*)(cp + 4);
    float d;
    d = zv - ca.x; dsq[0] = fmaf(d, d, dsq[0]);
    d = zv - ca.y; dsq[1] = fmaf(d, d, dsq[1]);
    d = zv - ca.z; dsq[2] = fmaf(d, d, dsq[2]);
    d = zv - ca.w; dsq[3] = fmaf(d, d, dsq[3]);
    d = zv - cb.x; dsq[4] = fmaf(d, d, dsq[4]);
    d = zv - cb.y; dsq[5] = fmaf(d, d, dsq[5]);
    d = zv - cb.z; dsq[6] = fmaf(d, d, dsq[6]);
    d = zv - cb.w; dsq[7] = fmaf(d, d, dsq[7]);
  }
  float lin[8];
#pragma unroll
  for (int u = 0; u < 8; ++u) lin[u] = slin[r][cg + 8 * u];

  const double EPS = 0.001;
  const double SQRTK = sqrt(128.0);
  const double z_sq = (double)z_sqf;
  double tau = SQRTK * fmax(1.0 - z_sq, 0.001) * 0.5;
  tau = fmax(tau, 0.01);
  const double inv_tau = 1.0 / tau;
  const double r2 = fmin(z_sq, 1.0 - EPS);
  const double lam_fac = (1.0 - r2 + EPS) * 0.5 / SQRTK;  // (1/lam)/sqrt(K)
  const double* __restrict__ csqd = (const double*)(ws + WS_CSQ);

  double sc[8];
#pragma unroll
  for (int u = 0; u < 8; ++u) {
    const int n = cg + 8 * u;
    const double c_sq = csqd[n];
    const double denom = (1.0 - z_sq) * (1.0 - c_sq);
    // R12: shifted-form arccosh in f32. d = arg-1 >= 0; clamp d to EPS
    // (== ref's arg = max(arg, 1+EPS)); all f32 operands positive.
    float df = 2.0f * dsq[u] / ((float)denom + 0.001f);
    df = fmaxf(df, 0.001f);
    const float root = sqrtf(df * (df + 2.0f));
    const float dist = log1pf(df + root);               // == arccosh(1+d)
    sc[u] = -(double)dist * inv_tau + (double)lin[u] * lam_fac;
  }
  __syncthreads();  // all cqT2/zt/slin reads done before s_exp overlay

  // per-thread max (n increasing -> strict '>' keeps lowest index)
  {
    double mx = sc[0];
    int am = cg;
#pragma unroll
    for (int u = 1; u < 8; ++u)
      if (sc[u] > mx) { mx = sc[u]; am = cg + 8 * u; }
    pmax[r][cg] = mx;
    parg[r][cg] = am;
  }
  __syncthreads();
  if (t < 32) {
    double m = pmax[t][0];
    int a = parg[t][0];
#pragma unroll
    for (int g = 1; g < 8; ++g) {
      const double v = pmax[t][g];
      const int aa = parg[t][g];
      if (v > m || (v == m && aa < a)) { m = v; a = aa; }
    }
    rowmax[t] = m;
    rowarg[t] = a;
  }
  __syncthreads();
  {
    const double m = rowmax[r];
    double ps = 0.0;
#pragma unroll
    for (int u = 0; u < 8; ++u) {
      // R12: f32 exp after fp64 max-subtraction (arg <= 0, no overflow)
      const double e = (double)expf((float)(sc[u] - m));
      s_exp[r][cg + 8 * u] = e;
      ps += e;
    }
    pmax[r][cg] = ps;
  }
  __syncthreads();
  if (t < 32) {
    double s = 0.0;
#pragma unroll
    for (int g = 0; g < 8; ++g) s += pmax[t][g];
    rowinv[t] = 1.0 / s;
  }
  __syncthreads();
  for (int idx = t; idx < 2048; idx += 256) {
    const int b = idx >> 6, n = idx & 63;
    out[(size_t)(b0 + b) * 64 + n] = (float)(s_exp[b][n] * rowinv[b]);
  }
  if (t < 32) out[(size_t)B_TOT * 64 + b0 + t] = (float)rowarg[t];
}

extern "C" void kernel_launch(void* const* d_in, const int* in_sizes, int n_in,
                              void* d_out, int out_size, void* d_ws, size_t ws_size,
                              hipStream_t stream) {
  const float* z = (const float*)d_in[0];
  const float* feat = (const float*)d_in[1];
  const float* qzw = (const float*)d_in[2];
  const float* qzb = (const float*)d_in[3];
  const float* qfw = (const float*)d_in[4];
  const float* qfb = (const float*)d_in[5];
  const float* gamma = (const float*)d_in[6];
  const float* cq = (const float*)d_in[7];
  float* out = (float*)d_out;
  char* ws = (char*)d_ws;  // requires ws_size >= 6033408

  prep_s<<<dim3(256), dim3(256), 0, stream>>>(gamma, cq, ws);
  prep_pack<<<dim3(256), dim3(256), 0, stream>>>(qfw, cq, qzw, qzb, qfb, ws);
  gemm_tail_kernel<<<dim3(B_TOT / 32), dim3(256), 0, stream>>>(z, feat, cq, ws, out);
}